// Round 6
// baseline (221.549 us; speedup 1.0000x reference)
//
#include <hip/hip_runtime.h>
#include <hip/hip_bf16.h>
#include <math.h>

#define B   8
#define S   64
#define NL  128
#define NPRO 256
#define NN  384   // NL + NPRO
#define P   64
#define NGRP 8
#define EPSF 1e-6f

// ---------------------------------------------------------------------------
// Kernel 1: mean_len[b,s]
// ---------------------------------------------------------------------------
__global__ __launch_bounds__(64) void meanlen_kernel(
    const float* __restrict__ lig, const float* __restrict__ ligmask,
    const float* __restrict__ pro, const float* __restrict__ promask,
    float* __restrict__ meanlen)
{
    int blk = blockIdx.x;              // b*S + s
    int t = threadIdx.x;
    float suml = 0.f, cnt = 0.f;

    const float* lbase = lig + (size_t)blk * NL * 3;
    const float* lm    = ligmask + (size_t)blk * NL;
    for (int n = t; n < NL; n += 64) {
        float x = lbase[n*3+0], y = lbase[n*3+1], z = lbase[n*3+2];
        float mk = lm[n];
        suml += sqrtf(x*x + y*y + z*z) * mk;
        cnt  += mk;
    }
    const float* pbase = pro + (size_t)blk * NPRO * 3;
    const float* pm    = promask + (size_t)blk * NPRO;
    for (int n = t; n < NPRO; n += 64) {
        float x = pbase[n*3+0], y = pbase[n*3+1], z = pbase[n*3+2];
        float mk = pm[n];
        suml += sqrtf(x*x + y*y + z*z) * mk;
        cnt  += mk;
    }
    for (int off = 32; off > 0; off >>= 1) {
        suml += __shfl_down(suml, off);
        cnt  += __shfl_down(cnt,  off);
    }
    if (t == 0) meanlen[blk] = suml / cnt;
}

// ---------------------------------------------------------------------------
// Kernel 2: SoA projection planes
// ---------------------------------------------------------------------------
__global__ __launch_bounds__(64) void proj_kernel(
    const float* __restrict__ lig, const float* __restrict__ pro,
    const float* __restrict__ ligmask, const float* __restrict__ promask,
    const float* __restrict__ ligw, const float* __restrict__ prow,
    const float* __restrict__ sw, const float* __restrict__ meanlen,
    float* __restrict__ projx, float* __restrict__ projy, float* __restrict__ projz)
{
    int blk = blockIdx.x;
    int b = blk / (NN / NGRP);
    int g = blk - b * (NN / NGRP);
    int nbase = g * NGRP;
    int t = threadIdx.x;
    bool isl = (nbase < NL);

    __shared__ float wl[64][65];           // wl[p][s], padded
    const float* w = isl ? ligw : prow;    // (P,S)
    for (int row = 0; row < 64; ++row) wl[row][t] = w[row * 64 + t];

    __shared__ float cs[NGRP][3][64];      // coords premultiplied by g-factor
    {
        int s = t;
        float gfac = sw[s] / (meanlen[b * S + s] + EPSF);
        for (int nn = 0; nn < NGRP; ++nn) {
            int n = nbase + nn;
            float mk, X, Y, Z;
            if (isl) {
                size_t base = ((size_t)b * S + s) * NL + n;
                mk = ligmask[base];
                X = lig[base*3+0]; Y = lig[base*3+1]; Z = lig[base*3+2];
            } else {
                size_t base = ((size_t)b * S + s) * NPRO + (n - NL);
                mk = promask[base];
                X = pro[base*3+0]; Y = pro[base*3+1]; Z = pro[base*3+2];
            }
            float gg = gfac * mk;
            cs[nn][0][s] = X * gg;
            cs[nn][1][s] = Y * gg;
            cs[nn][2][s] = Z * gg;
        }
    }
    __syncthreads();

    for (int nn = 0; nn < NGRP; ++nn) {
        float a0 = 0.f, a1 = 0.f, a2 = 0.f;
        #pragma unroll 8
        for (int s = 0; s < 64; ++s) {
            float wv = wl[t][s];
            a0 += cs[nn][0][s] * wv;
            a1 += cs[nn][1][s] * wv;
            a2 += cs[nn][2][s] * wv;
        }
        size_t base = ((size_t)b * NN + nbase + nn) * P;
        projx[base + t] = a0;
        projy[base + t] = a1;
        projz[base + t] = a2;
    }
}

// ---------------------------------------------------------------------------
// ABLATION V0: pure grid-stride stream of messages (4 passes).
// 2048 blocks x 256 thr = 524288 threads; 6291456 float4 total -> 12/thread.
// ---------------------------------------------------------------------------
__global__ __launch_bounds__(256) void ablate_stream(
    const float4* __restrict__ msg, float* __restrict__ scratch)
{
    size_t tid = (size_t)blockIdx.x * 256 + threadIdx.x;
    float4 acc = {0,0,0,0};
    #pragma unroll 1
    for (int pass = 0; pass < 4; ++pass) {
        for (size_t idx = tid; idx < 6291456ull; idx += 524288ull) {
            float4 v = msg[idx];
            acc.x += v.x; acc.y += v.y; acc.z += v.z; acc.w += v.w;
        }
        asm volatile("" ::: "memory");
    }
    scratch[tid] = acc.x + acc.y + acc.z + acc.w;
}

// ---------------------------------------------------------------------------
// ABLATION V1: per-(b,i)-slab stream (real kernel's grid shape), 4 passes.
// 1024 blocks x 256 thr; slab = 6144 float4 -> 24/thread.
// ---------------------------------------------------------------------------
__global__ __launch_bounds__(256) void ablate_slab(
    const float4* __restrict__ msg, float* __restrict__ scratch)
{
    const float4* base = msg + (size_t)blockIdx.x * 6144;
    float4 acc = {0,0,0,0};
    #pragma unroll 1
    for (int pass = 0; pass < 4; ++pass) {
        for (int k = threadIdx.x; k < 6144; k += 256) {
            float4 v = base[k];
            acc.x += v.x; acc.y += v.y; acc.z += v.z; acc.w += v.w;
        }
        asm volatile("" ::: "memory");
    }
    scratch[(size_t)blockIdx.x * 256 + threadIdx.x] = acc.x + acc.y + acc.z + acc.w;
}

// ---------------------------------------------------------------------------
// ABLATION V2: slab + mask + exp + S1/S2 softmax sums (no proj/geometry), 4 passes.
// ---------------------------------------------------------------------------
__global__ __launch_bounds__(256) void ablate_soft(
    const float* __restrict__ messages, const int* __restrict__ adj,
    float* __restrict__ scratch)
{
    int blk = blockIdx.x;
    int t = threadIdx.x;
    __shared__ float amask[NN];
    const int* adjb = adj + (size_t)blk * NN;
    for (int n = t; n < NN; n += 256)
        amask[n] = adjb[n] > 0 ? 0.f : -INFINITY;
    __syncthreads();

    const float4* m4 = (const float4*)(messages + (size_t)blk * NN * P);
    float4 S1 = {0,0,0,0}, S2 = {0,0,0,0};
    #pragma unroll 1
    for (int pass = 0; pass < 4; ++pass) {
        for (int k = t; k < 6144; k += 256) {
            int n = k >> 4;
            float am = amask[n];
            float4 v = m4[k];
            float e;
            asm("v_exp_f32 %0, %1" : "=v"(e) : "v"(fmaf(v.x, 1.44269504f, am)));
            S1.x += e; S2.x = fmaf(e, e, S2.x);
            asm("v_exp_f32 %0, %1" : "=v"(e) : "v"(fmaf(v.y, 1.44269504f, am)));
            S1.y += e; S2.y = fmaf(e, e, S2.y);
            asm("v_exp_f32 %0, %1" : "=v"(e) : "v"(fmaf(v.z, 1.44269504f, am)));
            S1.z += e; S2.z = fmaf(e, e, S2.z);
            asm("v_exp_f32 %0, %1" : "=v"(e) : "v"(fmaf(v.w, 1.44269504f, am)));
            S1.w += e; S2.w = fmaf(e, e, S2.w);
        }
        asm volatile("" ::: "memory");
    }
    scratch[(size_t)blk * 256 + t] = S1.x + S1.y + S1.z + S1.w + S2.x + S2.y + S2.z + S2.w;
}

// ---------------------------------------------------------------------------
// Kernel 3 (real, R3 i-pair version): fused softmax + geometry + projection.
// ---------------------------------------------------------------------------
#define PROC2(C) { \
    float d0 = xi0x.C - xx.C, d1 = xi0y.C - yy.C, d2 = xi0z.C - zz.C; \
    float sq = fmaf(d0, d0, fmaf(d1, d1, d2 * d2)); \
    float inv; asm("v_rsq_f32 %0, %1" : "=v"(inv) : "v"(sq)); \
    inv = fminf(inv, 1e30f); \
    float xe = fmaf(mm0.C, 1.44269504f, am0); \
    float e; asm("v_exp_f32 %0, %1" : "=v"(e) : "v"(xe)); \
    S1a.C += e; S2a.C = fmaf(e, e, S2a.C); \
    float ei = e * inv; \
    A0a.C = fmaf(ei, d0, A0a.C); A1a.C = fmaf(ei, d1, A1a.C); A2a.C = fmaf(ei, d2, A2a.C); \
    d0 = xi1x.C - xx.C; d1 = xi1y.C - yy.C; d2 = xi1z.C - zz.C; \
    sq = fmaf(d0, d0, fmaf(d1, d1, d2 * d2)); \
    asm("v_rsq_f32 %0, %1" : "=v"(inv) : "v"(sq)); \
    inv = fminf(inv, 1e30f); \
    xe = fmaf(mm1.C, 1.44269504f, am1); \
    asm("v_exp_f32 %0, %1" : "=v"(e) : "v"(xe)); \
    S1b.C += e; S2b.C = fmaf(e, e, S2b.C); \
    ei = e * inv; \
    A0b.C = fmaf(ei, d0, A0b.C); A1b.C = fmaf(ei, d1, A1b.C); A2b.C = fmaf(ei, d2, A2b.C); }

#define RED(V) { V.x += __shfl_xor(V.x, off); V.y += __shfl_xor(V.y, off); \
                 V.z += __shfl_xor(V.z, off); V.w += __shfl_xor(V.w, off); }

__global__ __launch_bounds__(512) void attn_kernel(
    const float* __restrict__ messages,   // (B, NL, NN, P)
    const int*   __restrict__ adj,        // (B, NL, NN)
    const float* __restrict__ projx,      // (B, NN, P)
    const float* __restrict__ projy,
    const float* __restrict__ projz,
    const float* __restrict__ attn_w,     // (S, P)
    float* __restrict__ out)              // (B, S, NL, 3)
{
    int blk = blockIdx.x;        // b*(NL/2) + ip
    int b = blk >> 6;
    int ip = blk & 63;
    int i0 = ip * 2;
    int i1 = i0 + 1;
    int t = threadIdx.x;
    int lane = t & 63;
    int wave = t >> 6;           // 0..7
    int pg = lane & 15;          // p-group: p = pg*4 .. pg*4+3
    int wsl = lane >> 4;         // 0..3
    int slice = wave * 4 + wsl;  // 0..31, n in [slice*12, slice*12+12)

    __shared__ float amask[2][NN];
    __shared__ __align__(16) float red[2][5][8][64];   // [i][acc][wave][p]
    __shared__ float upd[2][3][64];

    const int* adj0 = adj + ((size_t)b * NL + i0) * NN;
    const int* adj1 = adj + ((size_t)b * NL + i1) * NN;
    for (int n = t; n < NN; n += 512) {
        amask[0][n] = adj0[n] > 0 ? 0.f : -INFINITY;
        amask[1][n] = adj1[n] > 0 ? 0.f : -INFINITY;
    }

    const float4* m04 = (const float4*)messages + ((size_t)b * NL + i0) * NN * 16;
    const float4* m14 = (const float4*)messages + ((size_t)b * NL + i1) * NN * 16;
    const float4* px4 = (const float4*)projx + (size_t)b * NN * 16;
    const float4* py4 = (const float4*)projy + (size_t)b * NN * 16;
    const float4* pz4 = (const float4*)projz + (size_t)b * NN * 16;

    float4 xi0x = px4[(size_t)i0 * 16 + pg];
    float4 xi0y = py4[(size_t)i0 * 16 + pg];
    float4 xi0z = pz4[(size_t)i0 * 16 + pg];
    float4 xi1x = px4[(size_t)i1 * 16 + pg];
    float4 xi1y = py4[(size_t)i1 * 16 + pg];
    float4 xi1z = pz4[(size_t)i1 * 16 + pg];

    __syncthreads();

    float4 S1a = {0,0,0,0}, S2a = {0,0,0,0}, A0a = {0,0,0,0}, A1a = {0,0,0,0}, A2a = {0,0,0,0};
    float4 S1b = {0,0,0,0}, S2b = {0,0,0,0}, A0b = {0,0,0,0}, A1b = {0,0,0,0}, A2b = {0,0,0,0};

    int nb = slice * 12;
    size_t base = (size_t)nb * 16 + pg;

    float4 bm0[2], bm1[2], bx[2], by[2], bz[2];
    bm0[0] = m04[base];      bm1[0] = m14[base];
    bx[0]  = px4[base];      by[0]  = py4[base];      bz[0] = pz4[base];
    bm0[1] = m04[base + 16]; bm1[1] = m14[base + 16];
    bx[1]  = px4[base + 16]; by[1]  = py4[base + 16]; bz[1] = pz4[base + 16];

    #pragma unroll
    for (int k = 0; k < 12; ++k) {
        float4 mm0 = bm0[k & 1], mm1 = bm1[k & 1];
        float4 xx = bx[k & 1], yy = by[k & 1], zz = bz[k & 1];
        if (k < 10) {
            size_t idx = base + (size_t)(k + 2) * 16;
            bm0[k & 1] = m04[idx]; bm1[k & 1] = m14[idx];
            bx[k & 1]  = px4[idx]; by[k & 1]  = py4[idx]; bz[k & 1] = pz4[idx];
        }
        int n = nb + k;
        float am0 = amask[0][n], am1 = amask[1][n];
        PROC2(x) PROC2(y) PROC2(z) PROC2(w)
    }

    #pragma unroll
    for (int off = 16; off <= 32; off <<= 1) {
        RED(S1a) RED(S2a) RED(A0a) RED(A1a) RED(A2a)
        RED(S1b) RED(S2b) RED(A0b) RED(A1b) RED(A2b)
    }

    if (wsl == 0) {
        int pb = pg * 4;
        *(float4*)&red[0][0][wave][pb] = S1a; *(float4*)&red[0][1][wave][pb] = S2a;
        *(float4*)&red[0][2][wave][pb] = A0a; *(float4*)&red[0][3][wave][pb] = A1a;
        *(float4*)&red[0][4][wave][pb] = A2a;
        *(float4*)&red[1][0][wave][pb] = S1b; *(float4*)&red[1][1][wave][pb] = S2b;
        *(float4*)&red[1][2][wave][pb] = A0b; *(float4*)&red[1][3][wave][pb] = A1b;
        *(float4*)&red[1][4][wave][pb] = A2b;
    }
    __syncthreads();

    if (t < 128) {
        int il = t >> 6, p = t & 63;
        float s1 = 0.f, s2 = 0.f, a0 = 0.f, a1 = 0.f, a2 = 0.f;
        #pragma unroll
        for (int w = 0; w < 8; ++w) {
            s1 += red[il][0][w][p]; s2 += red[il][1][w][p];
            a0 += red[il][2][w][p]; a1 += red[il][3][w][p]; a2 += red[il][4][w][p];
        }
        float wgt = sqrtf(s2) / (s1 * s1);   // (A/S1)*sqrt(S2)/S1
        upd[il][0][p] = a0 * wgt;
        upd[il][1][p] = a1 * wgt;
        upd[il][2][p] = a2 * wgt;
    }
    __syncthreads();

    if (t < 384) {
        int il = t >= 192;
        int r = t - il * 192;
        int s = r & 63, c = r >> 6;
        int i = i0 + il;
        const float4* aw4 = (const float4*)attn_w + (size_t)s * 16;
        float o = 0.f;
        #pragma unroll
        for (int q = 0; q < 16; ++q) {
            float4 w4 = aw4[q];
            o = fmaf(upd[il][c][q*4+0], w4.x, o);
            o = fmaf(upd[il][c][q*4+1], w4.y, o);
            o = fmaf(upd[il][c][q*4+2], w4.z, o);
            o = fmaf(upd[il][c][q*4+3], w4.w, o);
        }
        out[(((size_t)b * S + s) * NL + i) * 3 + c] = o;
    }
}

extern "C" void kernel_launch(void* const* d_in, const int* in_sizes, int n_in,
                              void* d_out, int out_size, void* d_ws, size_t ws_size,
                              hipStream_t stream)
{
    const float* lig      = (const float*)d_in[0];   // (B,S,NL,3)
    const float* messages = (const float*)d_in[1];   // (B,NL,NN,P)
    const int*   adj      = (const int*)  d_in[2];   // (B,NL,NN)
    const float* ligmask  = (const float*)d_in[3];   // (B,S,NL)
    const float* pro      = (const float*)d_in[4];   // (B,S,NPRO,3)
    const float* promask  = (const float*)d_in[5];   // (B,S,NPRO)
    const float* ligw     = (const float*)d_in[6];   // (P,S)
    const float* prow     = (const float*)d_in[7];   // (P,S)
    const float* attnw    = (const float*)d_in[8];   // (S,P)
    const float* sw       = (const float*)d_in[9];   // (S,)
    float* out = (float*)d_out;

    const size_t plane = (size_t)B * NN * P;         // 196608 floats
    float* meanlen = (float*)d_ws;                               // 2 KB
    float* projx   = (float*)((char*)d_ws + 2048);
    float* projy   = projx + plane;
    float* projz   = projy + plane;

    meanlen_kernel<<<B * S, 64, 0, stream>>>(lig, ligmask, pro, promask, meanlen);
    proj_kernel<<<B * (NN / NGRP), 64, 0, stream>>>(lig, pro, ligmask, promask,
                                                    ligw, prow, sw, meanlen,
                                                    projx, projy, projz);
    attn_kernel<<<B * NL / 2, 512, 0, stream>>>(messages, adj, projx, projy, projz,
                                                attnw, out);

    // --- diagnostic ablations (write to high scratch; rocprof gives per-dispatch dur) ---
    if (ws_size >= 32u * 1024u * 1024u) {
        float* s0 = (float*)((char*)d_ws + 16u * 1024u * 1024u);  // 2 MB
        float* s1 = (float*)((char*)d_ws + 20u * 1024u * 1024u);  // 1 MB
        float* s2 = (float*)((char*)d_ws + 24u * 1024u * 1024u);  // 1 MB
        ablate_stream<<<2048, 256, 0, stream>>>((const float4*)messages, s0);
        ablate_slab<<<1024, 256, 0, stream>>>((const float4*)messages, s1);
        ablate_soft<<<1024, 256, 0, stream>>>(messages, adj, s2);
    }
}

// Round 7
// 59.860 us; speedup vs baseline: 3.7011x; 3.7011x over previous
//
#include <hip/hip_runtime.h>
#include <hip/hip_bf16.h>
#include <math.h>

#define B   8
#define S   64
#define NL  128
#define NPRO 256
#define NN  384   // NL + NPRO
#define P   64
#define NGRP 8
#define EPSF 1e-6f

// ---------------------------------------------------------------------------
// Kernel 1: mean_len[b,s]
// ---------------------------------------------------------------------------
__global__ __launch_bounds__(64) void meanlen_kernel(
    const float* __restrict__ lig, const float* __restrict__ ligmask,
    const float* __restrict__ pro, const float* __restrict__ promask,
    float* __restrict__ meanlen)
{
    int blk = blockIdx.x;              // b*S + s
    int t = threadIdx.x;
    float suml = 0.f, cnt = 0.f;

    const float* lbase = lig + (size_t)blk * NL * 3;
    const float* lm    = ligmask + (size_t)blk * NL;
    for (int n = t; n < NL; n += 64) {
        float x = lbase[n*3+0], y = lbase[n*3+1], z = lbase[n*3+2];
        float mk = lm[n];
        suml += sqrtf(x*x + y*y + z*z) * mk;
        cnt  += mk;
    }
    const float* pbase = pro + (size_t)blk * NPRO * 3;
    const float* pm    = promask + (size_t)blk * NPRO;
    for (int n = t; n < NPRO; n += 64) {
        float x = pbase[n*3+0], y = pbase[n*3+1], z = pbase[n*3+2];
        float mk = pm[n];
        suml += sqrtf(x*x + y*y + z*z) * mk;
        cnt  += mk;
    }
    for (int off = 32; off > 0; off >>= 1) {
        suml += __shfl_down(suml, off);
        cnt  += __shfl_down(cnt,  off);
    }
    if (t == 0) meanlen[blk] = suml / cnt;
}

// ---------------------------------------------------------------------------
// Kernel 2: SoA projection planes
// projc[b,n,p] = sum_s coord[b,s,n,c] * sw[s]/(mean+eps)*mask * w[p,s]
// ---------------------------------------------------------------------------
__global__ __launch_bounds__(64) void proj_kernel(
    const float* __restrict__ lig, const float* __restrict__ pro,
    const float* __restrict__ ligmask, const float* __restrict__ promask,
    const float* __restrict__ ligw, const float* __restrict__ prow,
    const float* __restrict__ sw, const float* __restrict__ meanlen,
    float* __restrict__ projx, float* __restrict__ projy, float* __restrict__ projz)
{
    int blk = blockIdx.x;
    int b = blk / (NN / NGRP);
    int g = blk - b * (NN / NGRP);
    int nbase = g * NGRP;
    int t = threadIdx.x;
    bool isl = (nbase < NL);

    __shared__ float wl[64][65];           // wl[p][s], padded
    const float* w = isl ? ligw : prow;    // (P,S)
    for (int row = 0; row < 64; ++row) wl[row][t] = w[row * 64 + t];

    __shared__ float cs[NGRP][3][64];      // coords premultiplied by g-factor
    {
        int s = t;
        float gfac = sw[s] / (meanlen[b * S + s] + EPSF);
        for (int nn = 0; nn < NGRP; ++nn) {
            int n = nbase + nn;
            float mk, X, Y, Z;
            if (isl) {
                size_t base = ((size_t)b * S + s) * NL + n;
                mk = ligmask[base];
                X = lig[base*3+0]; Y = lig[base*3+1]; Z = lig[base*3+2];
            } else {
                size_t base = ((size_t)b * S + s) * NPRO + (n - NL);
                mk = promask[base];
                X = pro[base*3+0]; Y = pro[base*3+1]; Z = pro[base*3+2];
            }
            float gg = gfac * mk;
            cs[nn][0][s] = X * gg;
            cs[nn][1][s] = Y * gg;
            cs[nn][2][s] = Z * gg;
        }
    }
    __syncthreads();

    for (int nn = 0; nn < NGRP; ++nn) {
        float a0 = 0.f, a1 = 0.f, a2 = 0.f;
        #pragma unroll 8
        for (int s = 0; s < 64; ++s) {
            float wv = wl[t][s];
            a0 += cs[nn][0][s] * wv;
            a1 += cs[nn][1][s] * wv;
            a2 += cs[nn][2][s] * wv;
        }
        size_t base = ((size_t)b * NN + nbase + nn) * P;
        projx[base + t] = a0;
        projy[base + t] = a1;
        projz[base + t] = a2;
    }
}

// ---------------------------------------------------------------------------
// Kernel 3 (dominant, pass 1): block = (b, n-eighth of 48, i-chunk of 16).
// Thread owns ONE p and 12 n's; proj for those n's is register-hoisted ONCE
// and reused across all 16 i -> single msg load stream in the hot loop.
// Per i: 12 scalar msg loads, 12-elem geometry+softmax, 4-wave LDS reduce,
// write partial[b,i,nh,{S1,S2,A0,A1,A2},p]. Ping-pong LDS: 1 barrier per i.
// grid = B*8*8 = 512 blocks x 256 threads (4 waves).
// ---------------------------------------------------------------------------
__global__ __launch_bounds__(256) void partial_kernel(
    const float* __restrict__ messages,   // (B, NL, NN, P)
    const int*   __restrict__ adj,        // (B, NL, NN)
    const float* __restrict__ projx,      // (B, NN, P)
    const float* __restrict__ projy,
    const float* __restrict__ projz,
    float* __restrict__ partial)          // (B*NL, 8, 5, 64)
{
    int blk = blockIdx.x;          // b*64 + nh*8 + ic
    int b  = blk >> 6;
    int nh = (blk >> 3) & 7;
    int ic = blk & 7;
    int t = threadIdx.x;
    int wave = t >> 6;             // 0..3
    int p = t & 63;
    int n0 = nh * 48 + wave * 12;  // this wave's 12 n's

    __shared__ float amk[16][48];              // additive mask per (il, q)
    __shared__ float wavepart[2][4][5][64];    // ping-pong reduce staging

    for (int idx = t; idx < 16 * 48; idx += 256) {
        int il = idx / 48, q = idx - il * 48;
        amk[il][q] = adj[((size_t)b * NL + ic * 16 + il) * NN + nh * 48 + q] > 0
                     ? 0.f : -INFINITY;
    }

    // hoist this thread's 12 proj points into registers (read once per block)
    float xnx[12], xny[12], xnz[12];
    size_t pbase = ((size_t)b * NN + n0) * 64 + p;
    #pragma unroll
    for (int k = 0; k < 12; ++k) {
        xnx[k] = projx[pbase + (size_t)k * 64];
        xny[k] = projy[pbase + (size_t)k * 64];
        xnz[k] = projz[pbase + (size_t)k * 64];
    }
    __syncthreads();

    #pragma unroll 1
    for (int il = 0; il < 16; ++il) {
        size_t row = (size_t)b * NL + ic * 16 + il;     // global i-row
        size_t xidx = ((size_t)b * NN + ic * 16 + il) * 64 + p;
        float xix = projx[xidx], xiy = projy[xidx], xiz = projz[xidx];

        const float* mb = messages + (row * NN + n0) * 64 + p;
        float m[12];
        #pragma unroll
        for (int k = 0; k < 12; ++k) m[k] = mb[(size_t)k * 64];

        float s1 = 0.f, s2 = 0.f, a0 = 0.f, a1 = 0.f, a2 = 0.f;
        #pragma unroll
        for (int k = 0; k < 12; ++k) {
            float am = amk[il][wave * 12 + k];          // LDS broadcast
            float d0 = xix - xnx[k], d1 = xiy - xny[k], d2 = xiz - xnz[k];
            float sq = fmaf(d0, d0, fmaf(d1, d1, d2 * d2));
            float inv; asm("v_rsq_f32 %0, %1" : "=v"(inv) : "v"(sq));
            inv = fminf(inv, 1e30f);                    // sq==0 -> d==0 -> contributes 0
            float xe = fmaf(m[k], 1.44269504f, am);     // exp2(m*log2e + {0,-inf})
            float e; asm("v_exp_f32 %0, %1" : "=v"(e) : "v"(xe));
            float ei = e * inv;
            s1 += e; s2 = fmaf(e, e, s2);
            a0 = fmaf(ei, d0, a0); a1 = fmaf(ei, d1, a1); a2 = fmaf(ei, d2, a2);
        }

        int buf = il & 1;
        wavepart[buf][wave][0][p] = s1;
        wavepart[buf][wave][1][p] = s2;
        wavepart[buf][wave][2][p] = a0;
        wavepart[buf][wave][3][p] = a1;
        wavepart[buf][wave][4][p] = a2;
        __syncthreads();   // lgkmcnt(0) drain => prev combine reads also done

        for (int idx = t; idx < 320; idx += 256) {
            int acc = idx >> 6, pp = idx & 63;
            float v = wavepart[buf][0][acc][pp] + wavepart[buf][1][acc][pp]
                    + wavepart[buf][2][acc][pp] + wavepart[buf][3][acc][pp];
            partial[((row * 8 + nh) * 5 + acc) * 64 + pp] = v;
        }
        // no 2nd barrier: next il writes the other buffer; the il+1 barrier
        // orders these reads before the il+2 writes of this buffer.
    }
}

// ---------------------------------------------------------------------------
// Kernel 4 (pass 2): combine the 8 n-partials, apply sqrt(S2)/S1^2, project
// to s. grid = B*NL blocks x 192 threads.
// ---------------------------------------------------------------------------
__global__ __launch_bounds__(192) void combine_kernel(
    const float* __restrict__ partial,    // (B*NL, 8, 5, 64)
    const float* __restrict__ attn_w,     // (S, P)
    float* __restrict__ out)              // (B, S, NL, 3)
{
    int blk = blockIdx.x;        // b*NL + i
    int b = blk >> 7;
    int i = blk & (NL - 1);
    int t = threadIdx.x;

    __shared__ float upd[3][64];

    if (t < 64) {
        float s1 = 0.f, s2 = 0.f, a0 = 0.f, a1 = 0.f, a2 = 0.f;
        #pragma unroll
        for (int nh = 0; nh < 8; ++nh) {
            size_t base = (((size_t)blk * 8 + nh) * 5) * 64 + t;
            s1 += partial[base];
            s2 += partial[base + 64];
            a0 += partial[base + 128];
            a1 += partial[base + 192];
            a2 += partial[base + 256];
        }
        float wgt = sqrtf(s2) / (s1 * s1);   // (A/S1)*sqrt(S2)/S1
        upd[0][t] = a0 * wgt;
        upd[1][t] = a1 * wgt;
        upd[2][t] = a2 * wgt;
    }
    __syncthreads();

    int s = t & 63, c = t >> 6;
    const float4* aw4 = (const float4*)attn_w + (size_t)s * 16;
    float o = 0.f;
    #pragma unroll
    for (int q = 0; q < 16; ++q) {
        float4 w4 = aw4[q];
        o = fmaf(upd[c][q*4+0], w4.x, o);
        o = fmaf(upd[c][q*4+1], w4.y, o);
        o = fmaf(upd[c][q*4+2], w4.z, o);
        o = fmaf(upd[c][q*4+3], w4.w, o);
    }
    out[(((size_t)b * S + s) * NL + i) * 3 + c] = o;
}

extern "C" void kernel_launch(void* const* d_in, const int* in_sizes, int n_in,
                              void* d_out, int out_size, void* d_ws, size_t ws_size,
                              hipStream_t stream)
{
    const float* lig      = (const float*)d_in[0];   // (B,S,NL,3)
    const float* messages = (const float*)d_in[1];   // (B,NL,NN,P)
    const int*   adj      = (const int*)  d_in[2];   // (B,NL,NN)
    const float* ligmask  = (const float*)d_in[3];   // (B,S,NL)
    const float* pro      = (const float*)d_in[4];   // (B,S,NPRO,3)
    const float* promask  = (const float*)d_in[5];   // (B,S,NPRO)
    const float* ligw     = (const float*)d_in[6];   // (P,S)
    const float* prow     = (const float*)d_in[7];   // (P,S)
    const float* attnw    = (const float*)d_in[8];   // (S,P)
    const float* sw       = (const float*)d_in[9];   // (S,)
    float* out = (float*)d_out;

    const size_t plane = (size_t)B * NN * P;         // 196608 floats
    float* meanlen = (float*)d_ws;                               // 2 KB
    float* projx   = (float*)((char*)d_ws + 2048);
    float* projy   = projx + plane;
    float* projz   = projy + plane;
    float* partial = (float*)((char*)d_ws + (4u << 20));         // 10.5 MB @ 4MB

    meanlen_kernel<<<B * S, 64, 0, stream>>>(lig, ligmask, pro, promask, meanlen);
    proj_kernel<<<B * (NN / NGRP), 64, 0, stream>>>(lig, pro, ligmask, promask,
                                                    ligw, prow, sw, meanlen,
                                                    projx, projy, projz);
    partial_kernel<<<B * 8 * 8, 256, 0, stream>>>(messages, adj,
                                                  projx, projy, projz, partial);
    combine_kernel<<<B * NL, 192, 0, stream>>>(partial, attnw, out);
}

// Round 8
// 57.388 us; speedup vs baseline: 3.8606x; 1.0431x over previous
//
#include <hip/hip_runtime.h>
#include <hip/hip_bf16.h>
#include <math.h>

#define B   8
#define S   64
#define NL  128
#define NPRO 256
#define NN  384   // NL + NPRO
#define P   64
#define NGRP 8
#define EPSF 1e-6f

// ---------------------------------------------------------------------------
// Kernel 1: mean_len[b,s]
// ---------------------------------------------------------------------------
__global__ __launch_bounds__(64) void meanlen_kernel(
    const float* __restrict__ lig, const float* __restrict__ ligmask,
    const float* __restrict__ pro, const float* __restrict__ promask,
    float* __restrict__ meanlen)
{
    int blk = blockIdx.x;              // b*S + s
    int t = threadIdx.x;
    float suml = 0.f, cnt = 0.f;

    const float* lbase = lig + (size_t)blk * NL * 3;
    const float* lm    = ligmask + (size_t)blk * NL;
    for (int n = t; n < NL; n += 64) {
        float x = lbase[n*3+0], y = lbase[n*3+1], z = lbase[n*3+2];
        float mk = lm[n];
        suml += sqrtf(x*x + y*y + z*z) * mk;
        cnt  += mk;
    }
    const float* pbase = pro + (size_t)blk * NPRO * 3;
    const float* pm    = promask + (size_t)blk * NPRO;
    for (int n = t; n < NPRO; n += 64) {
        float x = pbase[n*3+0], y = pbase[n*3+1], z = pbase[n*3+2];
        float mk = pm[n];
        suml += sqrtf(x*x + y*y + z*z) * mk;
        cnt  += mk;
    }
    for (int off = 32; off > 0; off >>= 1) {
        suml += __shfl_down(suml, off);
        cnt  += __shfl_down(cnt,  off);
    }
    if (t == 0) meanlen[blk] = suml / cnt;
}

// ---------------------------------------------------------------------------
// Kernel 2: SoA projection planes
// projc[b,n,p] = sum_s coord[b,s,n,c] * sw[s]/(mean+eps)*mask * w[p,s]
// ---------------------------------------------------------------------------
__global__ __launch_bounds__(64) void proj_kernel(
    const float* __restrict__ lig, const float* __restrict__ pro,
    const float* __restrict__ ligmask, const float* __restrict__ promask,
    const float* __restrict__ ligw, const float* __restrict__ prow,
    const float* __restrict__ sw, const float* __restrict__ meanlen,
    float* __restrict__ projx, float* __restrict__ projy, float* __restrict__ projz)
{
    int blk = blockIdx.x;
    int b = blk / (NN / NGRP);
    int g = blk - b * (NN / NGRP);
    int nbase = g * NGRP;
    int t = threadIdx.x;
    bool isl = (nbase < NL);

    __shared__ float wl[64][65];           // wl[p][s], padded
    const float* w = isl ? ligw : prow;    // (P,S)
    for (int row = 0; row < 64; ++row) wl[row][t] = w[row * 64 + t];

    __shared__ float cs[NGRP][3][64];      // coords premultiplied by g-factor
    {
        int s = t;
        float gfac = sw[s] / (meanlen[b * S + s] + EPSF);
        for (int nn = 0; nn < NGRP; ++nn) {
            int n = nbase + nn;
            float mk, X, Y, Z;
            if (isl) {
                size_t base = ((size_t)b * S + s) * NL + n;
                mk = ligmask[base];
                X = lig[base*3+0]; Y = lig[base*3+1]; Z = lig[base*3+2];
            } else {
                size_t base = ((size_t)b * S + s) * NPRO + (n - NL);
                mk = promask[base];
                X = pro[base*3+0]; Y = pro[base*3+1]; Z = pro[base*3+2];
            }
            float gg = gfac * mk;
            cs[nn][0][s] = X * gg;
            cs[nn][1][s] = Y * gg;
            cs[nn][2][s] = Z * gg;
        }
    }
    __syncthreads();

    for (int nn = 0; nn < NGRP; ++nn) {
        float a0 = 0.f, a1 = 0.f, a2 = 0.f;
        #pragma unroll 8
        for (int s = 0; s < 64; ++s) {
            float wv = wl[t][s];
            a0 += cs[nn][0][s] * wv;
            a1 += cs[nn][1][s] * wv;
            a2 += cs[nn][2][s] * wv;
        }
        size_t base = ((size_t)b * NN + nbase + nn) * P;
        projx[base + t] = a0;
        projy[base + t] = a1;
        projz[base + t] = a2;
    }
}

// ---------------------------------------------------------------------------
// Kernel 3 (dominant, pass 1): fully independent waves, no inner barriers.
// wave = (b, n-slice of 24, i-chunk of 4); lane = p. The 24 proj points are
// hoisted into 72 VGPRs once and reused across 4 i. n-reduction is purely
// intra-thread; per (i, wave) the 5 accumulators are written directly to
// partial[row, nsl, acc, p]. grid = 8b x 4g x 32ic = 1024 blocks x 256 thr
// (waves in a block differ only in nsl; they share the amask LDS stage).
// 16 waves/CU at <=128 VGPR (launch_bounds cap; msg loads batched 12+12).
// ---------------------------------------------------------------------------
__global__ __launch_bounds__(256, 4) void partial_kernel(
    const float* __restrict__ messages,   // (B, NL, NN, P)
    const int*   __restrict__ adj,        // (B, NL, NN)
    const float* __restrict__ projx,      // (B, NN, P)
    const float* __restrict__ projy,
    const float* __restrict__ projz,
    float* __restrict__ partial)          // (B*NL, 16, 5, 64)
{
    int blk = blockIdx.x;          // b*128 + g*32 + ic
    int b  = blk >> 7;
    int g  = (blk >> 5) & 3;       // n-quarter (96 n)
    int ic = blk & 31;             // i-chunk of 4
    int t = threadIdx.x;
    int wave = t >> 6;             // 0..3
    int p = t & 63;
    int nsl = g * 4 + wave;        // 0..15
    int n0 = nsl * 24;
    int i0 = ic * 4;

    __shared__ float amk[4][96];   // additive mask: 4 i x this block's 96 n

    for (int idx = t; idx < 4 * 96; idx += 256) {
        int il = idx / 96, q = idx - il * 96;
        amk[il][q] = adj[((size_t)b * NL + i0 + il) * NN + g * 96 + q] > 0
                     ? 0.f : -INFINITY;
    }

    // hoist this thread's 24 proj points (single batch of 72 loads, one drain)
    float xnx[24], xny[24], xnz[24];
    size_t pbase = ((size_t)b * NN + n0) * 64 + p;
    #pragma unroll
    for (int k = 0; k < 24; ++k) {
        xnx[k] = projx[pbase + (size_t)k * 64];
        xny[k] = projy[pbase + (size_t)k * 64];
        xnz[k] = projz[pbase + (size_t)k * 64];
    }
    __syncthreads();

    #pragma unroll 1
    for (int il = 0; il < 4; ++il) {
        int i = i0 + il;
        size_t row = (size_t)b * NL + i;
        size_t xidx = ((size_t)b * NN + i) * 64 + p;
        float xix = projx[xidx], xiy = projy[xidx], xiz = projz[xidx];

        const float* mb = messages + (row * NN + n0) * 64 + p;
        float s1 = 0.f, s2 = 0.f, a0 = 0.f, a1 = 0.f, a2 = 0.f;

        #pragma unroll
        for (int hb = 0; hb < 2; ++hb) {
            float m[12];
            #pragma unroll
            for (int k = 0; k < 12; ++k)
                m[k] = mb[(size_t)(hb * 12 + k) * 64];
            #pragma unroll
            for (int k = 0; k < 12; ++k) {
                int kk = hb * 12 + k;
                float am = amk[il][wave * 24 + kk];     // LDS broadcast
                float d0 = xix - xnx[kk], d1 = xiy - xny[kk], d2 = xiz - xnz[kk];
                float sq = fmaf(d0, d0, fmaf(d1, d1, d2 * d2));
                float inv; asm("v_rsq_f32 %0, %1" : "=v"(inv) : "v"(sq));
                inv = fminf(inv, 1e30f);                // sq==0 -> d==0 -> adds 0
                float xe = fmaf(m[k], 1.44269504f, am); // exp2(m*log2e + {0,-inf})
                float e; asm("v_exp_f32 %0, %1" : "=v"(e) : "v"(xe));
                float ei = e * inv;
                s1 += e; s2 = fmaf(e, e, s2);
                a0 = fmaf(ei, d0, a0); a1 = fmaf(ei, d1, a1); a2 = fmaf(ei, d2, a2);
            }
        }

        float* dst = partial + ((row * 16 + nsl) * 5) * 64 + p;
        dst[0]   = s1;
        dst[64]  = s2;
        dst[128] = a0;
        dst[192] = a1;
        dst[256] = a2;
    }
}

// ---------------------------------------------------------------------------
// Kernel 4 (pass 2): combine the 16 n-partials, apply sqrt(S2)/S1^2, project
// to s. grid = B*NL blocks x 192 threads.
// ---------------------------------------------------------------------------
__global__ __launch_bounds__(192) void combine_kernel(
    const float* __restrict__ partial,    // (B*NL, 16, 5, 64)
    const float* __restrict__ attn_w,     // (S, P)
    float* __restrict__ out)              // (B, S, NL, 3)
{
    int blk = blockIdx.x;        // b*NL + i
    int b = blk >> 7;
    int i = blk & (NL - 1);
    int t = threadIdx.x;

    __shared__ float upd[3][64];

    if (t < 64) {
        float s1 = 0.f, s2 = 0.f, a0 = 0.f, a1 = 0.f, a2 = 0.f;
        #pragma unroll
        for (int nh = 0; nh < 16; ++nh) {
            size_t base = (((size_t)blk * 16 + nh) * 5) * 64 + t;
            s1 += partial[base];
            s2 += partial[base + 64];
            a0 += partial[base + 128];
            a1 += partial[base + 192];
            a2 += partial[base + 256];
        }
        float wgt = sqrtf(s2) / (s1 * s1);   // (A/S1)*sqrt(S2)/S1
        upd[0][t] = a0 * wgt;
        upd[1][t] = a1 * wgt;
        upd[2][t] = a2 * wgt;
    }
    __syncthreads();

    int s = t & 63, c = t >> 6;
    const float4* aw4 = (const float4*)attn_w + (size_t)s * 16;
    float o = 0.f;
    #pragma unroll
    for (int q = 0; q < 16; ++q) {
        float4 w4 = aw4[q];
        o = fmaf(upd[c][q*4+0], w4.x, o);
        o = fmaf(upd[c][q*4+1], w4.y, o);
        o = fmaf(upd[c][q*4+2], w4.z, o);
        o = fmaf(upd[c][q*4+3], w4.w, o);
    }
    out[(((size_t)b * S + s) * NL + i) * 3 + c] = o;
}

extern "C" void kernel_launch(void* const* d_in, const int* in_sizes, int n_in,
                              void* d_out, int out_size, void* d_ws, size_t ws_size,
                              hipStream_t stream)
{
    const float* lig      = (const float*)d_in[0];   // (B,S,NL,3)
    const float* messages = (const float*)d_in[1];   // (B,NL,NN,P)
    const int*   adj      = (const int*)  d_in[2];   // (B,NL,NN)
    const float* ligmask  = (const float*)d_in[3];   // (B,S,NL)
    const float* pro      = (const float*)d_in[4];   // (B,S,NPRO,3)
    const float* promask  = (const float*)d_in[5];   // (B,S,NPRO)
    const float* ligw     = (const float*)d_in[6];   // (P,S)
    const float* prow     = (const float*)d_in[7];   // (P,S)
    const float* attnw    = (const float*)d_in[8];   // (S,P)
    const float* sw       = (const float*)d_in[9];   // (S,)
    float* out = (float*)d_out;

    const size_t plane = (size_t)B * NN * P;         // 196608 floats
    float* meanlen = (float*)d_ws;                               // 2 KB
    float* projx   = (float*)((char*)d_ws + 2048);
    float* projy   = projx + plane;
    float* projz   = projy + plane;
    float* partial = (float*)((char*)d_ws + (4u << 20));         // 21 MB @ 4MB

    meanlen_kernel<<<B * S, 64, 0, stream>>>(lig, ligmask, pro, promask, meanlen);
    proj_kernel<<<B * (NN / NGRP), 64, 0, stream>>>(lig, pro, ligmask, promask,
                                                    ligw, prow, sw, meanlen,
                                                    projx, projy, projz);
    partial_kernel<<<B * 4 * 32, 256, 0, stream>>>(messages, adj,
                                                   projx, projy, projz, partial);
    combine_kernel<<<B * NL, 192, 0, stream>>>(partial, attnw, out);
}